// Round 1
// baseline (107.400 us; speedup 1.0000x reference)
//
#include <hip/hip_runtime.h>
#include <math.h>

#define NE 8
#define ND 512
#define NB 16384
#define ND4 (ND / 4)   // 128 float4 per (b, expert) row

// Main kernel: entangled[b,i,d] = sum_j W[i,j] * x[b,j,d]
// Each thread owns one (b, d-quad): 8 coalesced float4 loads, 8x8x4 FMAs
// against W in LDS (broadcast reads), 8 coalesced float4 stores.
__global__ __launch_bounds__(256) void qe_entangle_kernel(
    const float* __restrict__ x, const float* __restrict__ C,
    float* __restrict__ out)
{
    __shared__ float Ws[NE * NE];
    const int t = threadIdx.x;
    if (t < NE * NE) {
        const int i = t >> 3, j = t & 7;
        const float c = C[t];
        Ws[t] = (i == j) ? 1.0f : (1.0f / (1.0f + __expf(-c)));
    }
    __syncthreads();

    const int total = NB * ND4;                 // 2,097,152 (b, d4) pairs
    const int stride = gridDim.x * blockDim.x;
    for (int idx = blockIdx.x * blockDim.x + t; idx < total; idx += stride) {
        const int b  = idx >> 7;                // / ND4
        const int d4 = idx & (ND4 - 1);

        const float4* xb = reinterpret_cast<const float4*>(x) + (size_t)b * (NE * ND4);
        float4 xv[NE];
        #pragma unroll
        for (int j = 0; j < NE; ++j)
            xv[j] = xb[j * ND4 + d4];

        float4* ob = reinterpret_cast<float4*>(out) + (size_t)b * (NE * ND4);
        #pragma unroll
        for (int i = 0; i < NE; ++i) {
            float4 a;
            a.x = 0.f; a.y = 0.f; a.z = 0.f; a.w = 0.f;
            #pragma unroll
            for (int j = 0; j < NE; ++j) {
                const float w = Ws[i * NE + j];
                a.x += w * xv[j].x;
                a.y += w * xv[j].y;
                a.z += w * xv[j].z;
                a.w += w * xv[j].w;
            }
            ob[i * ND4 + d4] = a;
        }
    }
}

// Trace kernel: recompute entangled[0] (8x512, reads 16 KiB — L2-hot),
// sum of squares, block-reduce, write scalar. One block, deterministic.
__global__ __launch_bounds__(256) void qe_trace_kernel(
    const float* __restrict__ x, const float* __restrict__ C,
    float* __restrict__ out)
{
    __shared__ float Ws[NE * NE];
    __shared__ float red[4];
    const int t = threadIdx.x;
    if (t < NE * NE) {
        const int i = t >> 3, j = t & 7;
        const float c = C[t];
        Ws[t] = (i == j) ? 1.0f : (1.0f / (1.0f + __expf(-c)));
    }
    __syncthreads();

    float acc = 0.f;
    for (int k = t; k < NE * ND; k += 256) {
        const int i = k >> 9;      // / ND
        const int d = k & (ND - 1);
        float s = 0.f;
        #pragma unroll
        for (int j = 0; j < NE; ++j)
            s += Ws[i * NE + j] * x[j * ND + d];
        acc += s * s;
    }
    // wave64 butterfly-free down-shuffle reduce
    #pragma unroll
    for (int off = 32; off > 0; off >>= 1)
        acc += __shfl_down(acc, off, 64);
    if ((t & 63) == 0) red[t >> 6] = acc;
    __syncthreads();
    if (t == 0) {
        const float s = red[0] + red[1] + red[2] + red[3];
        out[(size_t)NB * NE * ND] = fabsf(s) / ((float)(NE * ND) + 1e-8f);
    }
}

extern "C" void kernel_launch(void* const* d_in, const int* in_sizes, int n_in,
                              void* d_out, int out_size, void* d_ws, size_t ws_size,
                              hipStream_t stream) {
    const float* x = (const float*)d_in[0];   // [B, E, D] fp32
    const float* C = (const float*)d_in[1];   // [E, E] fp32
    float* out = (float*)d_out;               // [B*E*D] entangled + 1 scalar

    qe_entangle_kernel<<<2048, 256, 0, stream>>>(x, C, out);
    qe_trace_kernel<<<1, 256, 0, stream>>>(x, C, out);
}

// Round 3
// 91.513 us; speedup vs baseline: 1.1736x; 1.1736x over previous
//
#include <hip/hip_runtime.h>
#include <math.h>

#define NE 8
#define ND 512
#define NB 16384
#define ND4 (ND / 4)   // 128 float4 per (b, expert) row

typedef float f32x4 __attribute__((ext_vector_type(4)));

// Fused kernel:
//   entangled[b,i,d] = sum_j W[i,j] * x[b,j,d],  W = sigmoid(C) w/ unit diag.
// Each thread owns one (b, d-quad): 8 coalesced nontemporal 16B loads,
// 8x8x4 FMAs against W in LDS (broadcast reads), 8 nontemporal 16B stores.
// Trace fusion: with this index mapping, block 0 threads 0..127 compute all
// of entangled[0] in their first grid-stride iteration (b = idx>>7 == 0 iff
// idx < 128), so they square-accumulate in registers; block 0 then does a
// wave-shuffle + LDS reduction and writes the scalar. No second kernel.
__global__ __launch_bounds__(256) void qe_fused_kernel(
    const float* __restrict__ x, const float* __restrict__ C,
    float* __restrict__ out)
{
    __shared__ float Ws[NE * NE];
    __shared__ float red[4];
    const int t = threadIdx.x;
    if (t < NE * NE) {
        const int i = t >> 3, j = t & 7;
        const float c = C[t];
        Ws[t] = (i == j) ? 1.0f : (1.0f / (1.0f + __expf(-c)));
    }
    __syncthreads();

    float trace = 0.f;
    const int total = NB * ND4;                 // 2,097,152 (b, d4) pairs
    const int stride = gridDim.x * blockDim.x;
    for (int idx = blockIdx.x * blockDim.x + t; idx < total; idx += stride) {
        const int b  = idx >> 7;                // / ND4
        const int d4 = idx & (ND4 - 1);

        const f32x4* xb = reinterpret_cast<const f32x4*>(x)
                          + (size_t)b * (NE * ND4) + d4;
        f32x4 xv[NE];
        #pragma unroll
        for (int j = 0; j < NE; ++j)
            xv[j] = __builtin_nontemporal_load(&xb[(size_t)j * ND4]);

        f32x4* ob = reinterpret_cast<f32x4*>(out)
                    + (size_t)b * (NE * ND4) + d4;
        #pragma unroll
        for (int i = 0; i < NE; ++i) {
            f32x4 a = {0.f, 0.f, 0.f, 0.f};
            #pragma unroll
            for (int j = 0; j < NE; ++j) {
                const float w = Ws[i * NE + j];
                a.x = fmaf(w, xv[j].x, a.x);
                a.y = fmaf(w, xv[j].y, a.y);
                a.z = fmaf(w, xv[j].z, a.z);
                a.w = fmaf(w, xv[j].w, a.w);
            }
            __builtin_nontemporal_store(a, &ob[(size_t)i * ND4]);
            if (b == 0) {                       // wave-uniform, loop-invariant
                trace = fmaf(a.x, a.x, trace);
                trace = fmaf(a.y, a.y, trace);
                trace = fmaf(a.z, a.z, trace);
                trace = fmaf(a.w, a.w, trace);
            }
        }
    }

    if (blockIdx.x == 0) {
        // threads 128..255 carry trace == 0; reduce all 256 deterministically
        #pragma unroll
        for (int off = 32; off > 0; off >>= 1)
            trace += __shfl_down(trace, off, 64);
        if ((t & 63) == 0) red[t >> 6] = trace;
        __syncthreads();
        if (t == 0) {
            const float s = red[0] + red[1] + red[2] + red[3];
            out[(size_t)NB * NE * ND] = fabsf(s) / ((float)(NE * ND) + 1e-8f);
        }
    }
}

extern "C" void kernel_launch(void* const* d_in, const int* in_sizes, int n_in,
                              void* d_out, int out_size, void* d_ws, size_t ws_size,
                              hipStream_t stream) {
    const float* x = (const float*)d_in[0];   // [B, E, D] fp32
    const float* C = (const float*)d_in[1];   // [E, E] fp32
    float* out = (float*)d_out;               // [B*E*D] entangled + 1 scalar

    qe_fused_kernel<<<2048, 256, 0, stream>>>(x, C, out);
}

// Round 4
// 91.201 us; speedup vs baseline: 1.1776x; 1.0034x over previous
//
#include <hip/hip_runtime.h>
#include <math.h>

#define NE 8
#define ND 512
#define NB 16384
#define ND4 (ND / 4)   // 128 float4 per (b, expert) row

typedef float f32x4 __attribute__((ext_vector_type(4)));

// Fused kernel (exact-cover grid, one (b, d-quad) tile per thread, no loop):
//   entangled[b,i,d] = sum_j W[i,j] * x[b,j,d],  W = sigmoid(C) w/ unit diag.
// Each thread: 8 coalesced nontemporal 16B loads (one per expert j, stride
// 2KB; lanes contiguous -> 1KB/instr per wave), 8x8x4 FMAs against W in LDS
// (broadcast reads, conflict-free), 8 nontemporal 16B stores.
// Trace fusion: block 0 threads 0..127 own exactly b==0 (idx < 128), so they
// square-accumulate their freshly computed outputs in registers; block 0 then
// does a wave-shuffle + LDS reduction and writes the scalar. Deterministic.
__global__ __launch_bounds__(256) void qe_fused_kernel(
    const float* __restrict__ x, const float* __restrict__ C,
    float* __restrict__ out)
{
    __shared__ float Ws[NE * NE];
    __shared__ float red[4];
    const int t = threadIdx.x;
    if (t < NE * NE) {
        const int i = t >> 3, j = t & 7;
        const float c = C[t];
        Ws[t] = (i == j) ? 1.0f : (1.0f / (1.0f + __expf(-c)));
    }
    __syncthreads();

    const int idx = blockIdx.x * 256 + t;       // 0 .. NB*ND4-1, exact cover
    const int b  = idx >> 7;                    // / ND4
    const int d4 = idx & (ND4 - 1);

    const f32x4* xb = reinterpret_cast<const f32x4*>(x)
                      + (size_t)b * (NE * ND4) + d4;
    f32x4 xv[NE];
    #pragma unroll
    for (int j = 0; j < NE; ++j)
        xv[j] = __builtin_nontemporal_load(&xb[(size_t)j * ND4]);

    float trace = 0.f;
    f32x4* ob = reinterpret_cast<f32x4*>(out)
                + (size_t)b * (NE * ND4) + d4;
    #pragma unroll
    for (int i = 0; i < NE; ++i) {
        f32x4 a = {0.f, 0.f, 0.f, 0.f};
        #pragma unroll
        for (int j = 0; j < NE; ++j) {
            const float w = Ws[i * NE + j];
            a.x = fmaf(w, xv[j].x, a.x);
            a.y = fmaf(w, xv[j].y, a.y);
            a.z = fmaf(w, xv[j].z, a.z);
            a.w = fmaf(w, xv[j].w, a.w);
        }
        __builtin_nontemporal_store(a, &ob[(size_t)i * ND4]);
        if (b == 0) {                           // wave-uniform (only block 0)
            trace = fmaf(a.x, a.x, trace);
            trace = fmaf(a.y, a.y, trace);
            trace = fmaf(a.z, a.z, trace);
            trace = fmaf(a.w, a.w, trace);
        }
    }

    if (blockIdx.x == 0) {
        // threads 128..255 carry trace == 0; reduce all 256 deterministically
        #pragma unroll
        for (int off = 32; off > 0; off >>= 1)
            trace += __shfl_down(trace, off, 64);
        if ((t & 63) == 0) red[t >> 6] = trace;
        __syncthreads();
        if (t == 0) {
            const float s = red[0] + red[1] + red[2] + red[3];
            out[(size_t)NB * NE * ND] = fabsf(s) / ((float)(NE * ND) + 1e-8f);
        }
    }
}

extern "C" void kernel_launch(void* const* d_in, const int* in_sizes, int n_in,
                              void* d_out, int out_size, void* d_ws, size_t ws_size,
                              hipStream_t stream) {
    const float* x = (const float*)d_in[0];   // [B, E, D] fp32
    const float* C = (const float*)d_in[1];   // [E, E] fp32
    float* out = (float*)d_out;               // [B*E*D] entangled + 1 scalar

    qe_fused_kernel<<<(NB * ND4) / 256, 256, 0, stream>>>(x, C, out);
}